// Round 1
// 461.689 us; speedup vs baseline: 1.0670x; 1.0670x over previous
//
#include <hip/hip_runtime.h>

typedef __bf16 bf16x4 __attribute__((ext_vector_type(4)));
typedef __bf16 bf16x8 __attribute__((ext_vector_type(8)));
typedef float  f32x4  __attribute__((ext_vector_type(4)));

#define GLD16(gp, lp) __builtin_amdgcn_global_load_lds( \
    (const __attribute__((address_space(1))) void*)(gp), \
    (__attribute__((address_space(3))) void*)(lp), 16, 0, 0)

// ---------------------------------------------------------------------------
// fp32 -> bf16 one-shot convert (feat then fc_w, one grid)
// ---------------------------------------------------------------------------
__global__ __launch_bounds__(256) void convert_kernel(
    const float* __restrict__ feat, const float* __restrict__ w,
    __bf16* __restrict__ featb, __bf16* __restrict__ wb,
    long nFeat, long nW)
{
    long i = ((long)blockIdx.x * 256 + threadIdx.x) * 8;
    if (i < nFeat) {
        float4 a = *(const float4*)&feat[i];
        float4 b = *(const float4*)&feat[i + 4];
        bf16x8 o = {(__bf16)a.x,(__bf16)a.y,(__bf16)a.z,(__bf16)a.w,
                    (__bf16)b.x,(__bf16)b.y,(__bf16)b.z,(__bf16)b.w};
        *(bf16x8*)&featb[i] = o;
    } else {
        long j = i - nFeat;
        if (j < nW) {
            float4 a = *(const float4*)&w[j];
            float4 b = *(const float4*)&w[j + 4];
            bf16x8 o = {(__bf16)a.x,(__bf16)a.y,(__bf16)a.z,(__bf16)a.w,
                        (__bf16)b.x,(__bf16)b.y,(__bf16)b.z,(__bf16)b.w};
            *(bf16x8*)&wb[j] = o;
        }
    }
}

// ---------------------------------------------------------------------------
// 256x256-tile, BK=64, 8-wave (2Mx4N), 8-phase pipelined GEMM with counted
// vmcnt, XOR-swizzled LDS, setprio MFMA clusters, fused ghost-BN stats.
// C = A @ W^T,  x stored bf16, stats (scale/shift) fp32.
// ---------------------------------------------------------------------------
#define BAR()   __builtin_amdgcn_s_barrier()
#define LGKM0() do { asm volatile("s_waitcnt lgkmcnt(0)" ::: "memory"); \
                     __builtin_amdgcn_sched_barrier(0); } while (0)
#define VMW(n)  asm volatile("s_waitcnt vmcnt(" #n ")" ::: "memory")

__global__ __launch_bounds__(512, 2) void gemm8_bf16_kernel(
    const __bf16* __restrict__ A, const __bf16* __restrict__ W,
    __bf16* __restrict__ Xb, float* __restrict__ scale_o, float* __restrict__ shift_o,
    const float* __restrict__ gamma, const float* __restrict__ beta,
    int M, int N, int K)
{
    // [slot][half][128 rows x 64 k], 16B-granule XOR-swizzled within rows
    __shared__ __align__(16) __bf16 As[2][2][128 * 64];
    __shared__ __align__(16) __bf16 Bs[2][2][128 * 64];

    const int tid  = threadIdx.x;
    const int lane = tid & 63;
    const int w    = tid >> 6;     // wave 0..7
    const int wm   = w >> 2;       // 0..1  (M half)
    const int wn   = w & 3;        // 0..3  (N quarter)
    const int quad = lane >> 4;
    const int l16  = lane & 15;

    // bijective XCD swizzle (nb % 8 == 0 here: 8 x 64 = 512 blocks)
    const int nbx = gridDim.x;
    const int nb  = nbx * gridDim.y;
    int bid = blockIdx.y * nbx + blockIdx.x;
    int nid = bid;
    if ((nb & 7) == 0) nid = (bid & 7) * (nb >> 3) + (bid >> 3);
    const int bx = nid % nbx;
    const int by = nid / nbx;

    const int row0 = by * 256;
    const int col0 = bx * 256;

    // ---- staging source bases (pre-swizzled k-slot so LDS dest stays linear)
    const int sRow = lane >> 3;                 // 0..7 row within 8-row stripe
    const int sK   = ((lane & 7) ^ sRow) * 8;   // inverse-swizzled k offset
    const __bf16* pA = A + (size_t)(row0 + w * 8 + sRow) * K + sK;
    const __bf16* pB = W + (size_t)(col0 + (w >> 2) * 64 + (w & 3) * 8 + sRow) * K + sK;

    // A chunk c: rows c*64..c*64+63 of each half (linear)
#define STAGE_A(s, c, t) do { \
    const long koff_ = (long)(t) * 64; \
    GLD16(pA + (size_t)((c) * 64) * K + koff_,       &As[s][0][((c) * 64 + w * 8) * 64]); \
    GLD16(pA + (size_t)(128 + (c) * 64) * K + koff_, &As[s][1][((c) * 64 + w * 8) * 64]); \
  } while (0)
    // B chunk c: lds rows c*64..+63 hold actual rows with bits5/6 swapped
    // (groups the Q(j<2) rows {0-31,64-95} contiguously)
#define STAGE_B(s, c, t) do { \
    const long koff_ = (long)(t) * 64; \
    GLD16(pB + (size_t)((c) * 32) * K + koff_,       &Bs[s][0][((c) * 64 + w * 8) * 64]); \
    GLD16(pB + (size_t)(128 + (c) * 32) * K + koff_, &Bs[s][1][((c) * 64 + w * 8) * 64]); \
  } while (0)

    // ---- per-thread swizzled ds_read base offsets (bytes)
    const int swz0 = ((quad    ) ^ (l16 & 7)) * 16;   // kk = 0
    const int swz1 = ((quad ^ 4) ^ (l16 & 7)) * 16;   // kk = 1
    const int oA0 = l16 * 128 + swz0;
    const int oA1 = l16 * 128 + swz1;
    const int oB0 = ((wn & 1) * 32 + l16) * 128 + swz0;
    const int oB1 = ((wn & 1) * 32 + l16) * 128 + swz1;

    bf16x8 aF[2][4][2];   // [IH][ii][kk]
    bf16x8 bF[2][2][2];   // [JH][jj][kk]
    f32x4  acc[8][4];

#define LOADA(s, IH) do { \
    const char* ab_ = (const char*)&As[s][wm][0] + (IH) * 8192; \
    _Pragma("unroll") \
    for (int ii = 0; ii < 4; ++ii) { \
      aF[IH][ii][0] = *(const bf16x8*)(ab_ + ii * 2048 + oA0); \
      aF[IH][ii][1] = *(const bf16x8*)(ab_ + ii * 2048 + oA1); \
    } } while (0)
#define LOADB(s, JH) do { \
    const char* bb_ = (const char*)&Bs[s][wn >> 1][0] + (JH) * 8192; \
    _Pragma("unroll") \
    for (int jj = 0; jj < 2; ++jj) { \
      bF[JH][jj][0] = *(const bf16x8*)(bb_ + jj * 2048 + oB0); \
      bF[JH][jj][1] = *(const bf16x8*)(bb_ + jj * 2048 + oB1); \
    } } while (0)
#define MFMA_Q(IH, JH) do { \
    _Pragma("unroll") \
    for (int ii = 0; ii < 4; ++ii) \
    _Pragma("unroll") \
    for (int jj = 0; jj < 2; ++jj) { \
      acc[(IH)*4+ii][(JH)*2+jj] = __builtin_amdgcn_mfma_f32_16x16x32_bf16( \
          aF[IH][ii][0], bF[JH][jj][0], acc[(IH)*4+ii][(JH)*2+jj], 0, 0, 0); \
      acc[(IH)*4+ii][(JH)*2+jj] = __builtin_amdgcn_mfma_f32_16x16x32_bf16( \
          aF[IH][ii][1], bF[JH][jj][1], acc[(IH)*4+ii][(JH)*2+jj], 0, 0, 0); \
    } } while (0)

#pragma unroll
    for (int i = 0; i < 8; ++i)
#pragma unroll
      for (int j = 0; j < 4; ++j) { f32x4 z = {0.f,0.f,0.f,0.f}; acc[i][j] = z; }

    const int NT = K >> 6;

    // ---- prologue: tile0 complete + first half of tile1 (12 GLD/wave)
    STAGE_B(0, 0, 0);
    STAGE_A(0, 0, 0);
    STAGE_A(0, 1, 0);
    STAGE_B(0, 1, 0);
    STAGE_B(1, 0, 1);
    STAGE_A(1, 0, 1);
    VMW(4);              // tile 0 landed; B0_1/A03_1 (4 loads) stay in flight
    BAR();

    // ---- main loop: 4 phases per K-tile; vmcnt(4) only at tile boundary.
    // Staging schedule (derived race-free): ph1: A47_{t+1}, ph2: B1_{t+1},
    // ph3: B0_{t+2}, ph4: A03_{t+2}; every GLD issues >= 1 barrier after the
    // target region's last ds_read; every tile vmcnt-covered 1 phase early.
#pragma unroll 2
    for (int t = 0; t < NT; ++t) {
      const int s = t & 1;
      // P1: Q(A03,B0)
      LOADA(s, 0); LOADB(s, 0);
      if (t + 1 < NT) STAGE_A(s ^ 1, 1, t + 1);
      BAR(); LGKM0();
      __builtin_amdgcn_s_setprio(1); MFMA_Q(0, 0); __builtin_amdgcn_s_setprio(0);
      BAR();
      // P2: Q(A47,B0)
      LOADA(s, 1);
      if (t + 1 < NT) STAGE_B(s ^ 1, 1, t + 1);
      BAR(); LGKM0();
      __builtin_amdgcn_s_setprio(1); MFMA_Q(1, 0); __builtin_amdgcn_s_setprio(0);
      BAR();
      // P3: Q(A03,B1)
      LOADB(s, 1);
      if (t + 2 < NT) STAGE_B(s, 0, t + 2);
      BAR(); LGKM0();
      __builtin_amdgcn_s_setprio(1); MFMA_Q(0, 1); __builtin_amdgcn_s_setprio(0);
      BAR();
      // P4: Q(A47,B1)
      if (t + 2 < NT) STAGE_A(s, 0, t + 2);
      BAR(); LGKM0();
      __builtin_amdgcn_s_setprio(1); MFMA_Q(1, 1); __builtin_amdgcn_s_setprio(0);
      VMW(4);
      BAR();
    }

    // ---- epilogue: bf16 x store + per-wave-complete ghost-BN stats
    float psum[4] = {0,0,0,0}, pssq[4] = {0,0,0,0};
    const int rbase = row0 + wm * 128;
    const int cbase = col0 + wn * 64;
#pragma unroll
    for (int i = 0; i < 8; ++i)
#pragma unroll
      for (int j = 0; j < 4; ++j)
#pragma unroll
        for (int r = 0; r < 4; ++r) {
          float v = acc[i][j][r];
          int rr = rbase + i * 16 + quad * 4 + r;
          int cc = cbase + j * 16 + l16;
          Xb[(size_t)rr * N + cc] = (__bf16)v;
          psum[j] += v;
          pssq[j] += v * v;
        }
#pragma unroll
    for (int j = 0; j < 4; ++j) {
      psum[j] += __shfl_xor(psum[j], 16, 64);
      psum[j] += __shfl_xor(psum[j], 32, 64);
      pssq[j] += __shfl_xor(pssq[j], 16, 64);
      pssq[j] += __shfl_xor(pssq[j], 32, 64);
    }
    if (quad == 0) {
      const int g = (row0 >> 7) + wm;   // 128-row ghost group
#pragma unroll
      for (int j = 0; j < 4; ++j) {
        int cc = cbase + j * 16 + l16;
        float m    = psum[j] * (1.f / 128.f);
        float var  = pssq[j] * (1.f / 128.f) - m * m;
        float rstd = rsqrtf(var + 1e-5f);
        float a = rstd * gamma[cc];
        float b = beta[cc] - m * a;
        scale_o[(size_t)g * N + cc] = a;
        shift_o[(size_t)g * N + cc] = b;
      }
    }
}

// ---------------------------------------------------------------------------
// Stats reduction helper for the fp32 fallback GEMM
// ---------------------------------------------------------------------------
__device__ __forceinline__ void stats_reduce_store(
    float (&psum)[4], float (&pssq)[4],
    float* __restrict__ scale_o, float* __restrict__ shift_o,
    const float* __restrict__ gamma, const float* __restrict__ beta,
    float (*sred)[2][128],
    int row0, int col0, int N, int wm, int wn, int l16, int quad, int tid)
{
#pragma unroll
    for (int j = 0; j < 4; ++j) {
        psum[j] += __shfl_xor(psum[j], 16, 64);
        psum[j] += __shfl_xor(psum[j], 32, 64);
        pssq[j] += __shfl_xor(pssq[j], 16, 64);
        pssq[j] += __shfl_xor(pssq[j], 32, 64);
    }
    if (quad == 0) {
#pragma unroll
        for (int j = 0; j < 4; ++j) {
            int ccL = wn * 64 + j * 16 + l16;
            sred[wm][0][ccL] = psum[j];
            sred[wm][1][ccL] = pssq[j];
        }
    }
    __syncthreads();
    if (tid < 128) {
        float s  = sred[0][0][tid] + sred[1][0][tid];
        float ss = sred[0][1][tid] + sred[1][1][tid];
        float m  = s * (1.f / 128.f);
        float var = ss * (1.f / 128.f) - m * m;
        float rstd = rsqrtf(var + 1e-5f);
        int g = row0 >> 7;
        int col = col0 + tid;
        float a = rstd * gamma[col];
        float b = beta[col] - m * a;
        scale_o[(size_t)g * N + col] = a;
        shift_o[(size_t)g * N + col] = b;
    }
}

// ---------------------------------------------------------------------------
// Fallback GEMM (ws too small / odd shapes): fp32 inputs, fp32 x out
// ---------------------------------------------------------------------------
#define LDSS 40
__global__ __launch_bounds__(256) void gemm_f32_kernel(
    const float* __restrict__ A, const float* __restrict__ W,
    float* __restrict__ C, float* __restrict__ scale_o, float* __restrict__ shift_o,
    const float* __restrict__ gamma, const float* __restrict__ beta,
    int M, int N, int K)
{
    __shared__ __align__(16) __bf16 Asf[128 * LDSS];
    __shared__ __align__(16) __bf16 Bsf[128 * LDSS];
    __shared__ float sred[2][2][128];

    const int tid  = threadIdx.x;
    const int lane = tid & 63;
    const int wave = tid >> 6;
    const int wm   = wave >> 1;
    const int wn   = wave & 1;
    const int quad = lane >> 4;
    const int l16  = lane & 15;

    const int row0 = blockIdx.y * 128;
    const int col0 = blockIdx.x * 128;

    f32x4 acc[4][4];
#pragma unroll
    for (int i = 0; i < 4; ++i)
#pragma unroll
        for (int j = 0; j < 4; ++j) {
            f32x4 z = {0.f, 0.f, 0.f, 0.f};
            acc[i][j] = z;
        }

    for (int k0 = 0; k0 < K; k0 += 32) {
        __syncthreads();
#pragma unroll
        for (int i = 0; i < 4; ++i) {
            int chunk = tid + i * 256;
            int r  = chunk >> 3;
            int c4 = chunk & 7;
            float4 av = *(const float4*)&A[(size_t)(row0 + r) * K + k0 + c4 * 4];
            float4 bv = *(const float4*)&W[(size_t)(col0 + r) * K + k0 + c4 * 4];
            bf16x4 a16 = { (__bf16)av.x, (__bf16)av.y, (__bf16)av.z, (__bf16)av.w };
            bf16x4 b16 = { (__bf16)bv.x, (__bf16)bv.y, (__bf16)bv.z, (__bf16)bv.w };
            *(bf16x4*)&Asf[r * LDSS + c4 * 4] = a16;
            *(bf16x4*)&Bsf[r * LDSS + c4 * 4] = b16;
        }
        __syncthreads();

        bf16x8 af[4], bfv[4];
#pragma unroll
        for (int i = 0; i < 4; ++i)
            af[i]  = *(const bf16x8*)&Asf[(wm * 64 + i * 16 + l16) * LDSS + quad * 8];
#pragma unroll
        for (int j = 0; j < 4; ++j)
            bfv[j] = *(const bf16x8*)&Bsf[(wn * 64 + j * 16 + l16) * LDSS + quad * 8];

#pragma unroll
        for (int i = 0; i < 4; ++i)
#pragma unroll
            for (int j = 0; j < 4; ++j)
                acc[i][j] = __builtin_amdgcn_mfma_f32_16x16x32_bf16(af[i], bfv[j], acc[i][j], 0, 0, 0);
    }

    float psum[4] = {0,0,0,0}, pssq[4] = {0,0,0,0};
#pragma unroll
    for (int i = 0; i < 4; ++i)
#pragma unroll
        for (int j = 0; j < 4; ++j)
#pragma unroll
            for (int r = 0; r < 4; ++r) {
                float v = acc[i][j][r];
                int rr = row0 + wm * 64 + i * 16 + quad * 4 + r;
                int cc = col0 + wn * 64 + j * 16 + l16;
                C[(size_t)rr * N + cc] = v;
                psum[j] += v;
                pssq[j] += v * v;
            }
    stats_reduce_store(psum, pssq, scale_o, shift_o, gamma, beta, sred,
                       row0, col0, N, wm, wn, l16, quad, tid);
}

// ---------------------------------------------------------------------------
// BN-apply * priors -> sparsemax, bf16-x variant. One 256-thr block per row,
// 8 elems/lane; Michelot warm-started at tau0 = zmax-1. Requires N == 2048.
// ---------------------------------------------------------------------------
__device__ __forceinline__ float michelot_tau(
    const float (&z)[8], float mx, float (*red)[4][2], int lane, int wave)
{
    float tau   = mx - 1.0f;
    float kprev = -1.0f;
    for (int it = 0; it < 32; ++it) {
        float s = 0.f, c = 0.f;
#pragma unroll
        for (int i = 0; i < 8; ++i) {
            bool m = z[i] > tau;
            s += m ? z[i] : 0.f;
            c += m ? 1.f  : 0.f;
        }
#pragma unroll
        for (int m = 1; m < 64; m <<= 1) {
            s += __shfl_xor(s, m, 64);
            c += __shfl_xor(c, m, 64);
        }
        if (lane == 0) { red[it & 1][wave][0] = s; red[it & 1][wave][1] = c; }
        __syncthreads();
        s = red[it & 1][0][0] + red[it & 1][1][0] + red[it & 1][2][0] + red[it & 1][3][0];
        c = red[it & 1][0][1] + red[it & 1][1][1] + red[it & 1][2][1] + red[it & 1][3][1];
        float tnew = (s - 1.0f) / c;
        bool done = (c == kprev);     // block-uniform (from reduced values)
        kprev = c;
        tau = tnew;
        if (done) break;              // support unchanged -> tau exact
    }
    return tau;
}

__global__ __launch_bounds__(256) void bn_sparsemax_bf16_kernel(
    const __bf16* __restrict__ xb,
    float* __restrict__ outp,
    const float* __restrict__ priors,
    const float* __restrict__ scale_s,
    const float* __restrict__ shift_s,
    int N)
{
    __shared__ float red[2][4][2];
    __shared__ float mred[4];

    const int tid  = threadIdx.x;
    const int lane = tid & 63;
    const int wave = tid >> 6;
    const int row  = blockIdx.x;
    const int g    = row >> 7;            // VBS = 128
    const size_t base  = (size_t)row * N;
    const size_t gbase = (size_t)g * N;
    const int c0 = tid * 4;
    const int c1 = 1024 + tid * 4;        // order-invariant split

    bf16x4 xh0 = *(const bf16x4*)&xb[base + c0];
    bf16x4 xh1 = *(const bf16x4*)&xb[base + c1];
    float4 p0 = *(const float4*)&priors[base + c0];
    float4 p1 = *(const float4*)&priors[base + c1];
    float4 a0 = *(const float4*)&scale_s[gbase + c0];
    float4 a1 = *(const float4*)&scale_s[gbase + c1];
    float4 b0 = *(const float4*)&shift_s[gbase + c0];
    float4 b1 = *(const float4*)&shift_s[gbase + c1];

    float z[8];
    z[0] = fmaf((float)xh0[0], a0.x, b0.x) * p0.x;
    z[1] = fmaf((float)xh0[1], a0.y, b0.y) * p0.y;
    z[2] = fmaf((float)xh0[2], a0.z, b0.z) * p0.z;
    z[3] = fmaf((float)xh0[3], a0.w, b0.w) * p0.w;
    z[4] = fmaf((float)xh1[0], a1.x, b1.x) * p1.x;
    z[5] = fmaf((float)xh1[1], a1.y, b1.y) * p1.y;
    z[6] = fmaf((float)xh1[2], a1.z, b1.z) * p1.z;
    z[7] = fmaf((float)xh1[3], a1.w, b1.w) * p1.w;

    float mx = z[0];
#pragma unroll
    for (int i = 1; i < 8; ++i) mx = fmaxf(mx, z[i]);
#pragma unroll
    for (int m = 1; m < 64; m <<= 1) mx = fmaxf(mx, __shfl_xor(mx, m, 64));
    if (lane == 0) mred[wave] = mx;
    __syncthreads();
    mx = fmaxf(fmaxf(mred[0], mred[1]), fmaxf(mred[2], mred[3]));

    float tau = michelot_tau(z, mx, red, lane, wave);

    float4 o0, o1;
    o0.x = fmaxf(z[0] - tau, 0.f);
    o0.y = fmaxf(z[1] - tau, 0.f);
    o0.z = fmaxf(z[2] - tau, 0.f);
    o0.w = fmaxf(z[3] - tau, 0.f);
    o1.x = fmaxf(z[4] - tau, 0.f);
    o1.y = fmaxf(z[5] - tau, 0.f);
    o1.z = fmaxf(z[6] - tau, 0.f);
    o1.w = fmaxf(z[7] - tau, 0.f);
    *(float4*)&outp[base + c0] = o0;
    *(float4*)&outp[base + c1] = o1;
}

// fp32-x variant (fallback path; in-place on d_out)
__global__ __launch_bounds__(256) void bn_sparsemax_f32_kernel(
    float* __restrict__ x,
    const float* __restrict__ priors,
    const float* __restrict__ scale_s,
    const float* __restrict__ shift_s,
    int N)
{
    __shared__ float red[2][4][2];
    __shared__ float mred[4];

    const int tid  = threadIdx.x;
    const int lane = tid & 63;
    const int wave = tid >> 6;
    const int row  = blockIdx.x;
    const int g    = row >> 7;
    const size_t base  = (size_t)row * N;
    const size_t gbase = (size_t)g * N;
    const int c0 = tid * 4;
    const int c1 = 1024 + tid * 4;

    float4 x0 = *(const float4*)&x[base + c0];
    float4 x1 = *(const float4*)&x[base + c1];
    float4 p0 = *(const float4*)&priors[base + c0];
    float4 p1 = *(const float4*)&priors[base + c1];
    float4 a0 = *(const float4*)&scale_s[gbase + c0];
    float4 a1 = *(const float4*)&scale_s[gbase + c1];
    float4 b0 = *(const float4*)&shift_s[gbase + c0];
    float4 b1 = *(const float4*)&shift_s[gbase + c1];

    float z[8];
    z[0] = fmaf(x0.x, a0.x, b0.x) * p0.x;
    z[1] = fmaf(x0.y, a0.y, b0.y) * p0.y;
    z[2] = fmaf(x0.z, a0.z, b0.z) * p0.z;
    z[3] = fmaf(x0.w, a0.w, b0.w) * p0.w;
    z[4] = fmaf(x1.x, a1.x, b1.x) * p1.x;
    z[5] = fmaf(x1.y, a1.y, b1.y) * p1.y;
    z[6] = fmaf(x1.z, a1.z, b1.z) * p1.z;
    z[7] = fmaf(x1.w, a1.w, b1.w) * p1.w;

    float mx = z[0];
#pragma unroll
    for (int i = 1; i < 8; ++i) mx = fmaxf(mx, z[i]);
#pragma unroll
    for (int m = 1; m < 64; m <<= 1) mx = fmaxf(mx, __shfl_xor(mx, m, 64));
    if (lane == 0) mred[wave] = mx;
    __syncthreads();
    mx = fmaxf(fmaxf(mred[0], mred[1]), fmaxf(mred[2], mred[3]));

    float tau = michelot_tau(z, mx, red, lane, wave);

    float4 o0, o1;
    o0.x = fmaxf(z[0] - tau, 0.f);
    o0.y = fmaxf(z[1] - tau, 0.f);
    o0.z = fmaxf(z[2] - tau, 0.f);
    o0.w = fmaxf(z[3] - tau, 0.f);
    o1.x = fmaxf(z[4] - tau, 0.f);
    o1.y = fmaxf(z[5] - tau, 0.f);
    o1.z = fmaxf(z[6] - tau, 0.f);
    o1.w = fmaxf(z[7] - tau, 0.f);
    *(float4*)&x[base + c0] = o0;
    *(float4*)&x[base + c1] = o1;
}

// ---------------------------------------------------------------------------
extern "C" void kernel_launch(void* const* d_in, const int* in_sizes, int n_in,
                              void* d_out, int out_size, void* d_ws, size_t ws_size,
                              hipStream_t stream)
{
    const float* priors = (const float*)d_in[0];
    const float* feat   = (const float*)d_in[1];
    const float* fc_w   = (const float*)d_in[2];
    const float* gamma  = (const float*)d_in[3];
    const float* beta   = (const float*)d_in[4];
    float* out = (float*)d_out;

    const int G = in_sizes[3];               // 2048
    const int K = in_sizes[2] / G;           // 2048
    const int B = in_sizes[1] / K;           // 16384
    const int nGroups = B / 128;             // 128

    const size_t statsElems = (size_t)nGroups * G;
    float* scale_s = (float*)d_ws;
    float* shift_s = scale_s + statsElems;
    char* wsAfterStats = (char*)(shift_s + statsElems);

    const size_t nFeat = (size_t)B * K;
    const size_t nW    = (size_t)G * K;
    const size_t nX    = (size_t)B * G;
    const size_t statsBytes = 2 * statsElems * sizeof(float);
    const size_t needBf16   = statsBytes + (nFeat + nW) * sizeof(__bf16);
    const size_t needXb     = needBf16 + nX * sizeof(__bf16);

    const bool shapeOk = (B % 256 == 0) && (G % 256 == 0) &&
                         (K % 64 == 0) && (K >= 128);

    if (ws_size >= needXb && shapeOk) {
        // fast path: bf16 operands + 256^2 8-phase pipelined GEMM + bf16 x
        __bf16* featb = (__bf16*)wsAfterStats;
        __bf16* wb    = featb + nFeat;
        __bf16* xb    = wb + nW;
        long totalChunks = (long)((nFeat + nW) / 8);
        convert_kernel<<<(totalChunks + 255) / 256, 256, 0, stream>>>(
            feat, fc_w, featb, wb, (long)nFeat, (long)nW);
        gemm8_bf16_kernel<<<dim3(G / 256, B / 256), 512, 0, stream>>>(
            featb, wb, xb, scale_s, shift_s, gamma, beta, B, G, K);
        bn_sparsemax_bf16_kernel<<<B, 256, 0, stream>>>(
            xb, out, priors, scale_s, shift_s, G);
    } else {
        gemm_f32_kernel<<<dim3(G / 128, B / 128), 256, 0, stream>>>(
            feat, fc_w, out, scale_s, shift_s, gamma, beta, B, G, K);
        bn_sparsemax_f32_kernel<<<B, 256, 0, stream>>>(
            out, priors, scale_s, shift_s, G);
    }
}